// Round 6
// baseline (281.534 us; speedup 1.0000x reference)
//
#include <hip/hip_runtime.h>

#define NN 50000
#define EE 800000
#define GG 64
#define CC 8

#define NBKT 196      // ceil(50000/256) node buckets of 256
#define NCHK 782      // edge chunks = grid of k0 (1024 edges each)
#define CHUNK 1024
#define CAP 8192      // max edges per bucket (mean 4082)
#define NB8G 6250     // agg grids: NN/8 (R18: 2 nodes per wave)

// done-ticket for fused pool+sigmoid (196-block grid ONLY — R11 lesson: never on big grids)
__device__ unsigned g_done = 0;

__device__ __forceinline__ float lrelu(float z) { return fmaxf(z, 0.2f * z); }
__device__ __forceinline__ unsigned short f2bf(float v) {
    unsigned u = __float_as_uint(v);
    return (unsigned short)((u + 0x7FFFu + ((u >> 16) & 1u)) >> 16);  // RNE
}
__device__ __forceinline__ float bf2f(unsigned short b) {
    return __uint_as_float(((unsigned)b) << 16);
}
// unpack 2 bf16 from one dword: 1 VALU op per value
__device__ __forceinline__ float2 bf2x2(unsigned d) {
    float2 r;
    r.x = __uint_as_float(d << 16);
    r.y = __uint_as_float(d & 0xFFFF0000u);
    return r;
}

// ---------------- k0: layer-1 matmul (CSR-independent) fused with edge histogram ----------------
// R14 lesson: hist stays in LDS (global atomics = ~40 µs/800k-pass).
// R16 lesson: 196 buckets — k1's column reads of G scale with bucket count.

__global__ __launch_bounds__(256) void k0_mm11_hist(const float* __restrict__ x, const float* __restrict__ W,
                                                    const float* __restrict__ avs, const float* __restrict__ avd,
                                                    unsigned short* __restrict__ h, float* __restrict__ as_,
                                                    float* __restrict__ ad_, const int* __restrict__ dst,
                                                    int* __restrict__ G) {
    __shared__ float xT[11 * 68];
    __shared__ float Wl[11 * 64];
    __shared__ float avl[64], adl[64];
    __shared__ int hist[NBKT];
    int t = threadIdx.x;
    int nbase = blockIdx.x * 64;
    for (int idx = t; idx < 11 * 64; idx += 256) Wl[idx] = W[idx];
    if (t < 64) { avl[t] = avs[t]; adl[t] = avd[t]; }
    for (int idx = t; idx < 64 * 11; idx += 256) {
        int n = idx / 11, k = idx - n * 11;
        int gn = nbase + n;
        if (gn >= NN) gn = NN - 1;
        xT[k * 68 + n] = x[gn * 11 + k];
    }
    for (int i = t; i < NBKT; i += 256) hist[i] = 0;
    __syncthreads();
    int f0 = (t & 15) * 4;
    int n0 = (t >> 4) * 4;
    float a00=0,a01=0,a02=0,a03=0, a10=0,a11=0,a12=0,a13=0;
    float a20=0,a21=0,a22=0,a23=0, a30=0,a31=0,a32=0,a33=0;
#pragma unroll
    for (int k = 0; k < 11; k++) {
        float4 xv = *(const float4*)&xT[k * 68 + n0];
        float4 wv = *(const float4*)&Wl[k * 64 + f0];
        a00 += xv.x * wv.x; a01 += xv.x * wv.y; a02 += xv.x * wv.z; a03 += xv.x * wv.w;
        a10 += xv.y * wv.x; a11 += xv.y * wv.y; a12 += xv.y * wv.z; a13 += xv.y * wv.w;
        a20 += xv.z * wv.x; a21 += xv.z * wv.y; a22 += xv.z * wv.z; a23 += xv.z * wv.w;
        a30 += xv.w * wv.x; a31 += xv.w * wv.y; a32 += xv.w * wv.z; a33 += xv.w * wv.w;
    }
    float4 av = *(const float4*)&avl[f0];
    float4 dv = *(const float4*)&adl[f0];
    float vs[4], vd[4];
    vs[0] = a00*av.x + a01*av.y + a02*av.z + a03*av.w;
    vs[1] = a10*av.x + a11*av.y + a12*av.z + a13*av.w;
    vs[2] = a20*av.x + a21*av.y + a22*av.z + a23*av.w;
    vs[3] = a30*av.x + a31*av.y + a32*av.z + a33*av.w;
    vd[0] = a00*dv.x + a01*dv.y + a02*dv.z + a03*dv.w;
    vd[1] = a10*dv.x + a11*dv.y + a12*dv.z + a13*dv.w;
    vd[2] = a20*dv.x + a21*dv.y + a22*dv.z + a23*dv.w;
    vd[3] = a30*dv.x + a31*dv.y + a32*dv.z + a33*dv.w;
#pragma unroll
    for (int o = 1; o < 16; o <<= 1) {
#pragma unroll
        for (int ni = 0; ni < 4; ni++) {
            vs[ni] += __shfl_xor(vs[ni], o);
            vd[ni] += __shfl_xor(vd[ni], o);
        }
    }
    ushort4* h4 = (ushort4*)h;
    int nn0 = nbase + n0;
    float rows[4][4] = {{a00,a01,a02,a03},{a10,a11,a12,a13},{a20,a21,a22,a23},{a30,a31,a32,a33}};
#pragma unroll
    for (int ni = 0; ni < 4; ni++) {
        if (nn0 + ni < NN) {
            ushort4 pv;
            pv.x = f2bf(rows[ni][0]); pv.y = f2bf(rows[ni][1]);
            pv.z = f2bf(rows[ni][2]); pv.w = f2bf(rows[ni][3]);
            h4[(nn0 + ni) * 16 + (t & 15)] = pv;
            if ((t & 15) == 0) { as_[nn0 + ni] = vs[ni]; ad_[nn0 + ni] = vd[ni]; }
        }
    }
    int e0 = blockIdx.x * CHUNK;
    int e1 = min(e0 + CHUNK, EE);
    for (int e = e0 + t; e < e1; e += 256) atomicAdd(&hist[dst[e] >> 8], 1);
    __syncthreads();
    for (int i = t; i < NBKT; i += 256) G[blockIdx.x * NBKT + i] = hist[i];
}

// ---------------- k1: per-bucket scan across chunks; block 0 zeroes pool/cntf ----------------

__global__ __launch_bounds__(256) void k1_scan(const int* __restrict__ G, int* __restrict__ offs,
                                               int* __restrict__ bT, float* __restrict__ pool,
                                               float* __restrict__ cntf, int* __restrict__ rowptr) {
    __shared__ int s[256];
    int t = threadIdx.x, j = blockIdx.x;
    int c0 = t * 4;
    int v0 = (c0 + 0 < NCHK) ? G[(c0 + 0) * NBKT + j] : 0;
    int v1 = (c0 + 1 < NCHK) ? G[(c0 + 1) * NBKT + j] : 0;
    int v2 = (c0 + 2 < NCHK) ? G[(c0 + 2) * NBKT + j] : 0;
    int v3 = (c0 + 3 < NCHK) ? G[(c0 + 3) * NBKT + j] : 0;
    int tsum = v0 + v1 + v2 + v3;
    s[t] = tsum;
    __syncthreads();
#pragma unroll
    for (int off = 1; off < 256; off <<= 1) {
        int u = (t >= off) ? s[t - off] : 0;
        __syncthreads();
        s[t] += u;
        __syncthreads();
    }
    int excl = s[t] - tsum;
    if (c0 + 0 < NCHK) offs[(c0 + 0) * NBKT + j] = excl;
    if (c0 + 1 < NCHK) offs[(c0 + 1) * NBKT + j] = excl + v0;
    if (c0 + 2 < NCHK) offs[(c0 + 2) * NBKT + j] = excl + v0 + v1;
    if (c0 + 3 < NCHK) offs[(c0 + 3) * NBKT + j] = excl + v0 + v1 + v2;
    if (t == 255) bT[j] = s[255];
    if (j == 0) {
        for (int i = t; i < GG * CC; i += 256) pool[i] = 0.f;
        if (t < GG) cntf[t] = 0.f;
        if (t == 0) rowptr[NN] = EE;
    }
}

// ---------------- k2: partition edges into bucket-ordered packed pairs ----------------

__global__ __launch_bounds__(256) void k2_part(const int* __restrict__ src, const int* __restrict__ dst,
                                               const int* __restrict__ offs, const int* __restrict__ bT,
                                               unsigned* __restrict__ pairs) {
    __shared__ int s[256];
    __shared__ int bst[NBKT];
    __shared__ int cur[NBKT];
    int t = threadIdx.x, c = blockIdx.x;
    int v = (t < NBKT) ? bT[t] : 0;
    s[t] = v;
    __syncthreads();
#pragma unroll
    for (int off = 1; off < 256; off <<= 1) {
        int u = (t >= off) ? s[t - off] : 0;
        __syncthreads();
        s[t] += u;
        __syncthreads();
    }
    if (t < NBKT) bst[t] = s[t] - v;
    __syncthreads();
    for (int i = t; i < NBKT; i += 256) cur[i] = bst[i] + offs[c * NBKT + i];
    __syncthreads();
    int e0 = c * CHUNK, e1 = min(e0 + CHUNK, EE);
    for (int e = e0 + t; e < e1; e += 256) {
        int d = dst[e];
        int pos = atomicAdd(&cur[d >> 8], 1);
        pairs[pos] = (unsigned)src[e] | ((unsigned)(d & 255) << 16);  // src<2^16, dlocal<2^8
    }
}

// ---------------- k3: per-bucket counting sort -> col + rowptr ----------------

__global__ __launch_bounds__(256) void k3_sort(const unsigned* __restrict__ pairs, const int* __restrict__ bT,
                                               int* __restrict__ col, int* __restrict__ rowptr) {
    __shared__ unsigned pL[CAP];
    __shared__ int hist[256];
    __shared__ int sc[256];
    int t = threadIdx.x, j = blockIdx.x;
    int v = (t < NBKT) ? bT[t] : 0;
    hist[t] = v;
    __syncthreads();
#pragma unroll
    for (int off = 1; off < 256; off <<= 1) {
        int u = (t >= off) ? hist[t - off] : 0;
        __syncthreads();
        hist[t] += u;
        __syncthreads();
    }
    if (t == j) { sc[0] = hist[t] - v; sc[1] = v; }
    __syncthreads();
    int start = sc[0];
    int cnt = sc[1];
    if (cnt > CAP) cnt = CAP;
    int nb = j * 256;
    int nodeCnt = min(256, NN - nb);
    __syncthreads();
    hist[t] = 0;
    __syncthreads();
    for (int i = t; i < cnt; i += 256) {
        unsigned p = pairs[start + i];
        pL[i] = p;
        atomicAdd(&hist[p >> 16], 1);
    }
    __syncthreads();
    int c2 = hist[t];
    sc[t] = c2;
    __syncthreads();
#pragma unroll
    for (int off = 1; off < 256; off <<= 1) {
        int u = (t >= off) ? sc[t - off] : 0;
        __syncthreads();
        sc[t] += u;
        __syncthreads();
    }
    int excl = sc[t] - c2;
    if (t < nodeCnt) rowptr[nb + t] = start + excl;
    hist[t] = excl;
    __syncthreads();
    for (int i = t; i < cnt; i += 256) {
        unsigned p = pL[i];
        int pos = atomicAdd(&hist[p >> 16], 1);
        col[start + pos] = (int)(p & 0xFFFFu);
    }
}

// ---------------- tiled h = x @ W (64->64); bf16 in, bf16 out ----------------

__global__ __launch_bounds__(256) void k_mm64t(const unsigned short* __restrict__ xin,
                                               const float* __restrict__ W,
                                               const float* __restrict__ avs, const float* __restrict__ avd,
                                               unsigned short* __restrict__ h, float* __restrict__ as_,
                                               float* __restrict__ ad_) {
    __shared__ float xT[64 * 68];
    __shared__ float Wl[64 * 64];
    __shared__ float avl[64], adl[64];
    int t = threadIdx.x;
    int nbase = blockIdx.x * 64;
    for (int idx = t; idx < 64 * 64; idx += 256) Wl[idx] = W[idx];
    if (t < 64) { avl[t] = avs[t]; adl[t] = avd[t]; }
    for (int idx = t; idx < 64 * 64; idx += 256) {
        int n = idx / 64, k = idx - n * 64;
        int gn = nbase + n;
        if (gn >= NN) gn = NN - 1;
        xT[k * 68 + n] = bf2f(xin[gn * 64 + k]);
    }
    __syncthreads();
    int f0 = (t & 15) * 4;
    int n0 = (t >> 4) * 4;
    float a00=0,a01=0,a02=0,a03=0, a10=0,a11=0,a12=0,a13=0;
    float a20=0,a21=0,a22=0,a23=0, a30=0,a31=0,a32=0,a33=0;
#pragma unroll 4
    for (int k = 0; k < 64; k++) {
        float4 xv = *(const float4*)&xT[k * 68 + n0];
        float4 wv = *(const float4*)&Wl[k * 64 + f0];
        a00 += xv.x * wv.x; a01 += xv.x * wv.y; a02 += xv.x * wv.z; a03 += xv.x * wv.w;
        a10 += xv.y * wv.x; a11 += xv.y * wv.y; a12 += xv.y * wv.z; a13 += xv.y * wv.w;
        a20 += xv.z * wv.x; a21 += xv.z * wv.y; a22 += xv.z * wv.z; a23 += xv.z * wv.w;
        a30 += xv.w * wv.x; a31 += xv.w * wv.y; a32 += xv.w * wv.z; a33 += xv.w * wv.w;
    }
    float4 av = *(const float4*)&avl[f0];
    float4 dv = *(const float4*)&adl[f0];
    float vs[4], vd[4];
    vs[0] = a00*av.x + a01*av.y + a02*av.z + a03*av.w;
    vs[1] = a10*av.x + a11*av.y + a12*av.z + a13*av.w;
    vs[2] = a20*av.x + a21*av.y + a22*av.z + a23*av.w;
    vs[3] = a30*av.x + a31*av.y + a32*av.z + a33*av.w;
    vd[0] = a00*dv.x + a01*dv.y + a02*dv.z + a03*dv.w;
    vd[1] = a10*dv.x + a11*dv.y + a12*dv.z + a13*dv.w;
    vd[2] = a20*dv.x + a21*dv.y + a22*dv.z + a23*dv.w;
    vd[3] = a30*dv.x + a31*dv.y + a32*dv.z + a33*dv.w;
#pragma unroll
    for (int o = 1; o < 16; o <<= 1) {
#pragma unroll
        for (int ni = 0; ni < 4; ni++) {
            vs[ni] += __shfl_xor(vs[ni], o);
            vd[ni] += __shfl_xor(vd[ni], o);
        }
    }
    ushort4* h4 = (ushort4*)h;
    int nn0 = nbase + n0;
    float rows[4][4] = {{a00,a01,a02,a03},{a10,a11,a12,a13},{a20,a21,a22,a23},{a30,a31,a32,a33}};
#pragma unroll
    for (int ni = 0; ni < 4; ni++) {
        if (nn0 + ni < NN) {
            ushort4 pv;
            pv.x = f2bf(rows[ni][0]); pv.y = f2bf(rows[ni][1]);
            pv.z = f2bf(rows[ni][2]); pv.w = f2bf(rows[ni][3]);
            h4[(nn0 + ni) * 16 + (t & 15)] = pv;
            if ((t & 15) == 0) { as_[nn0 + ni] = vs[ni]; ad_[nn0 + ni] = vd[ni]; }
        }
    }
}

// ---------------- agg64 device bodies ----------------
// R18: agg64 is gather-LATENCY-bound (R13/R17 issue-count fixes were neutral). Each wave
// now owns TWO nodes (A/B register sets); all of A's and B's loads issue before any math,
// doubling per-wave outstanding gathers. Shuffle reduces are shared wave-wide rounds.

// single-node fast path (used when the partner node is in fallback)
template <int KMAX>
__device__ __forceinline__ void agg64_fast(int deg, int rp0, const int* __restrict__ col,
                                           const float* __restrict__ as_, float adn, float zself,
                                           const uint4* __restrict__ hb4, int node, int f, int eg,
                                           float (&acc)[8]) {
    uint4 rowreg[KMAX];
    float zk[KMAX];
#pragma unroll
    for (int k = 0; k < KMAX; k++) {
        int e = k * 8 + eg;
        zk[k] = -1e30f;
        rowreg[k] = make_uint4(0u, 0u, 0u, 0u);
        if (k < KMAX - 1 || e < deg) {
            int se = col[rp0 + e];
            zk[k] = lrelu(as_[se] + adn);
            rowreg[k] = hb4[se * 8 + f];
        }
    }
    float M = zk[0];
#pragma unroll
    for (int k = 1; k < KMAX; k++) M = fmaxf(M, zk[k]);
#pragma unroll
    for (int o = 8; o <= 32; o <<= 1) M = fmaxf(M, __shfl_xor(M, o));
    M = fmaxf(M, zself);
    float s0 = 0.f;
#pragma unroll
    for (int k = 0; k < KMAX; k++) { zk[k] = __expf(zk[k] - M); s0 += zk[k]; }
    float exs = __expf(zself - M);
    float sum = s0;
#pragma unroll
    for (int o = 8; o <= 32; o <<= 1) sum += __shfl_xor(sum, o);
    float inv = 1.f / (sum + exs);
#pragma unroll
    for (int k = 0; k < KMAX; k++) {
        float w = zk[k] * inv;
        float2 p0 = bf2x2(rowreg[k].x), p1 = bf2x2(rowreg[k].y);
        float2 p2 = bf2x2(rowreg[k].z), p3 = bf2x2(rowreg[k].w);
        acc[0] += w * p0.x; acc[1] += w * p0.y;
        acc[2] += w * p1.x; acc[3] += w * p1.y;
        acc[4] += w * p2.x; acc[5] += w * p2.y;
        acc[6] += w * p3.x; acc[7] += w * p3.y;
    }
    if (eg == 0) {
        float w0 = exs * inv;
        uint4 hv = hb4[node * 8 + f];
        float2 p0 = bf2x2(hv.x), p1 = bf2x2(hv.y), p2 = bf2x2(hv.z), p3 = bf2x2(hv.w);
        acc[0] += w0 * p0.x; acc[1] += w0 * p0.y;
        acc[2] += w0 * p1.x; acc[3] += w0 * p1.y;
        acc[4] += w0 * p2.x; acc[5] += w0 * p2.y;
        acc[6] += w0 * p3.x; acc[7] += w0 * p3.y;
    }
}

__device__ __forceinline__ void agg64_fast_dispatch(int deg, int rp0, const int* col, const float* as_,
                                                    float adn, float zself, const uint4* hb4, int node,
                                                    int f, int eg, float (&acc)[8]) {
    int kmax = max(1, (deg + 7) >> 3);
    switch (kmax) {
        case 1: agg64_fast<1>(deg, rp0, col, as_, adn, zself, hb4, node, f, eg, acc); break;
        case 2: agg64_fast<2>(deg, rp0, col, as_, adn, zself, hb4, node, f, eg, acc); break;
        case 3: agg64_fast<3>(deg, rp0, col, as_, adn, zself, hb4, node, f, eg, acc); break;
        default: agg64_fast<4>(deg, rp0, col, as_, adn, zself, hb4, node, f, eg, acc); break;
    }
}

// two-node batched fast path: all loads for A and B issue first (2x MLP)
template <int KMAX>
__device__ __forceinline__ void agg64_fast2(int degA, int rpA, int degB, int rpB,
                                            const int* __restrict__ col, const float* __restrict__ as_,
                                            float adnA, float zselfA, float adnB, float zselfB,
                                            const uint4* __restrict__ hb4, int nodeA, int nodeB,
                                            int f, int eg, float (&accA)[8], float (&accB)[8]) {
    uint4 rowA[KMAX], rowB[KMAX];
    float zA[KMAX], zB[KMAX];
#pragma unroll
    for (int k = 0; k < KMAX; k++) {
        int e = k * 8 + eg;
        zA[k] = -1e30f; rowA[k] = make_uint4(0u, 0u, 0u, 0u);
        if (e < degA) {
            int se = col[rpA + e];
            zA[k] = lrelu(as_[se] + adnA);
            rowA[k] = hb4[se * 8 + f];
        }
        zB[k] = -1e30f; rowB[k] = make_uint4(0u, 0u, 0u, 0u);
        if (e < degB) {
            int se = col[rpB + e];
            zB[k] = lrelu(as_[se] + adnB);
            rowB[k] = hb4[se * 8 + f];
        }
    }
    float MA = zA[0], MB = zB[0];
#pragma unroll
    for (int k = 1; k < KMAX; k++) { MA = fmaxf(MA, zA[k]); MB = fmaxf(MB, zB[k]); }
#pragma unroll
    for (int o = 8; o <= 32; o <<= 1) {
        MA = fmaxf(MA, __shfl_xor(MA, o));
        MB = fmaxf(MB, __shfl_xor(MB, o));
    }
    MA = fmaxf(MA, zselfA); MB = fmaxf(MB, zselfB);
    float sA = 0.f, sB = 0.f;
#pragma unroll
    for (int k = 0; k < KMAX; k++) {
        zA[k] = __expf(zA[k] - MA); sA += zA[k];
        zB[k] = __expf(zB[k] - MB); sB += zB[k];
    }
    float exsA = __expf(zselfA - MA), exsB = __expf(zselfB - MB);
#pragma unroll
    for (int o = 8; o <= 32; o <<= 1) {
        sA += __shfl_xor(sA, o);
        sB += __shfl_xor(sB, o);
    }
    float invA = 1.f / (sA + exsA), invB = 1.f / (sB + exsB);
#pragma unroll
    for (int k = 0; k < KMAX; k++) {
        float wA = zA[k] * invA;
        float2 a0 = bf2x2(rowA[k].x), a1 = bf2x2(rowA[k].y);
        float2 a2 = bf2x2(rowA[k].z), a3 = bf2x2(rowA[k].w);
        accA[0] += wA * a0.x; accA[1] += wA * a0.y;
        accA[2] += wA * a1.x; accA[3] += wA * a1.y;
        accA[4] += wA * a2.x; accA[5] += wA * a2.y;
        accA[6] += wA * a3.x; accA[7] += wA * a3.y;
        float wB = zB[k] * invB;
        float2 b0 = bf2x2(rowB[k].x), b1 = bf2x2(rowB[k].y);
        float2 b2 = bf2x2(rowB[k].z), b3 = bf2x2(rowB[k].w);
        accB[0] += wB * b0.x; accB[1] += wB * b0.y;
        accB[2] += wB * b1.x; accB[3] += wB * b1.y;
        accB[4] += wB * b2.x; accB[5] += wB * b2.y;
        accB[6] += wB * b3.x; accB[7] += wB * b3.y;
    }
    if (eg == 0) {
        float w0A = exsA * invA;
        uint4 hvA = hb4[nodeA * 8 + f];
        float2 a0 = bf2x2(hvA.x), a1 = bf2x2(hvA.y), a2 = bf2x2(hvA.z), a3 = bf2x2(hvA.w);
        accA[0] += w0A * a0.x; accA[1] += w0A * a0.y;
        accA[2] += w0A * a1.x; accA[3] += w0A * a1.y;
        accA[4] += w0A * a2.x; accA[5] += w0A * a2.y;
        accA[6] += w0A * a3.x; accA[7] += w0A * a3.y;
        float w0B = exsB * invB;
        uint4 hvB = hb4[nodeB * 8 + f];
        float2 b0 = bf2x2(hvB.x), b1 = bf2x2(hvB.y), b2 = bf2x2(hvB.z), b3 = bf2x2(hvB.w);
        accB[0] += w0B * b0.x; accB[1] += w0B * b0.y;
        accB[2] += w0B * b1.x; accB[3] += w0B * b1.y;
        accB[4] += w0B * b2.x; accB[5] += w0B * b2.y;
        accB[6] += w0B * b3.x; accB[7] += w0B * b3.y;
    }
}

// rare fallback (deg>32): online softmax + direct gathers, full wave on one node
__device__ void agg64_fallback(int deg, int rp0, const int* __restrict__ col,
                               const float* __restrict__ as_, float adn, float zself,
                               const uint4* __restrict__ hb4, int node, int lane, int f, int eg,
                               float (&acc)[8]) {
    float m = -1e30f, l = 0.f;
    for (int i = lane; i < deg; i += 64) {
        float z = lrelu(as_[col[rp0 + i]] + adn);
        float mn = fmaxf(m, z);
        l = l * __expf(m - mn) + __expf(z - mn);
        m = mn;
    }
    if (lane == 0) {
        float mn = fmaxf(m, zself);
        l = l * __expf(m - mn) + __expf(zself - mn);
        m = mn;
    }
#pragma unroll
    for (int o = 32; o; o >>= 1) {
        float mo = __shfl_xor(m, o), lo = __shfl_xor(l, o);
        float mn = fmaxf(m, mo);
        l = l * __expf(m - mn) + lo * __expf(mo - mn);
        m = mn;
    }
    float Em = m;
    float inv = 1.f / l;
    for (int base = 0; base < deg; base += 8) {
        int i = base + eg;
        if (i < deg) {
            int sv = col[rp0 + i];
            float al = __expf(lrelu(as_[sv] + adn) - Em) * inv;
            uint4 hv = hb4[sv * 8 + f];
            float2 p0 = bf2x2(hv.x), p1 = bf2x2(hv.y), p2 = bf2x2(hv.z), p3 = bf2x2(hv.w);
            acc[0] += al * p0.x; acc[1] += al * p0.y;
            acc[2] += al * p1.x; acc[3] += al * p1.y;
            acc[4] += al * p2.x; acc[5] += al * p2.y;
            acc[6] += al * p3.x; acc[7] += al * p3.y;
        }
    }
    if (eg == 0) {
        float al = __expf(zself - Em) * inv;
        uint4 hv = hb4[node * 8 + f];
        float2 p0 = bf2x2(hv.x), p1 = bf2x2(hv.y), p2 = bf2x2(hv.z), p3 = bf2x2(hv.w);
        acc[0] += al * p0.x; acc[1] += al * p0.y;
        acc[2] += al * p1.x; acc[3] += al * p1.y;
        acc[4] += al * p2.x; acc[5] += al * p2.y;
        acc[6] += al * p3.x; acc[7] += al * p3.y;
    }
}

// ---------------- GAT aggregation, 64 features, 2 nodes/wave ----------------

template <bool FUSE>
__global__ __launch_bounds__(256) void k_agg64(const unsigned short* __restrict__ h,
                                               const int* __restrict__ rowptr,
                                               const int* __restrict__ col, const float* __restrict__ as_,
                                               const float* __restrict__ ad_, const float* __restrict__ bias,
                                               unsigned short* __restrict__ out16,
                                               const float* __restrict__ W3, const float* __restrict__ a3s,
                                               const float* __restrict__ a3d,
                                               float* __restrict__ as3, float* __restrict__ ad3) {
    __shared__ float W3p[64 * 9];  // FUSE only; pad 8->9: 2-way conflicts only (free, m136)
    if constexpr (FUSE) {
        for (int idx = threadIdx.x; idx < 512; idx += 256)
            W3p[(idx >> 3) * 9 + (idx & 7)] = W3[idx];
        __syncthreads();  // uniform: before any divergence
    }
    int wid = threadIdx.x >> 6;
    int lane = threadIdx.x & 63;
    int nodeA = blockIdx.x * 8 + wid * 2;   // NN = 6250*8: every wave valid
    int nodeB = nodeA + 1;
    int rpA = rowptr[nodeA];
    int rpB = rowptr[nodeB];
    int degA = rpB - rpA;
    int degB = rowptr[nodeB + 1] - rpB;
    float adnA = ad_[nodeA], adnB = ad_[nodeB];
    float zselfA = lrelu(as_[nodeA] + adnA);
    float zselfB = lrelu(as_[nodeB] + adnB);
    const uint4* hb4 = (const uint4*)h;   // row = 8 x uint4 (8 bf16 per uint4)
    int f = lane & 7, eg = lane >> 3;     // 8 edges in parallel, 16B per lane
    float accA[8] = {0.f, 0.f, 0.f, 0.f, 0.f, 0.f, 0.f, 0.f};
    float accB[8] = {0.f, 0.f, 0.f, 0.f, 0.f, 0.f, 0.f, 0.f};
    if (degA <= 32 && degB <= 32) {
        int kmax = max(1, max((degA + 7) >> 3, (degB + 7) >> 3));  // wave-uniform
        switch (kmax) {
            case 1: agg64_fast2<1>(degA, rpA, degB, rpB, col, as_, adnA, zselfA, adnB, zselfB,
                                   hb4, nodeA, nodeB, f, eg, accA, accB); break;
            case 2: agg64_fast2<2>(degA, rpA, degB, rpB, col, as_, adnA, zselfA, adnB, zselfB,
                                   hb4, nodeA, nodeB, f, eg, accA, accB); break;
            case 3: agg64_fast2<3>(degA, rpA, degB, rpB, col, as_, adnA, zselfA, adnB, zselfB,
                                   hb4, nodeA, nodeB, f, eg, accA, accB); break;
            default: agg64_fast2<4>(degA, rpA, degB, rpB, col, as_, adnA, zselfA, adnB, zselfB,
                                    hb4, nodeA, nodeB, f, eg, accA, accB); break;
        }
    } else {  // rare: at least one node deg>32 — process each node with full wave
        if (degA <= 32) agg64_fast_dispatch(degA, rpA, col, as_, adnA, zselfA, hb4, nodeA, f, eg, accA);
        else            agg64_fallback(degA, rpA, col, as_, adnA, zselfA, hb4, nodeA, lane, f, eg, accA);
        if (degB <= 32) agg64_fast_dispatch(degB, rpB, col, as_, adnB, zselfB, hb4, nodeB, f, eg, accB);
        else            agg64_fallback(degB, rpB, col, as_, adnB, zselfB, hb4, nodeB, lane, f, eg, accB);
    }
    // reduce across the 8 eg groups; after this ALL lanes hold features f*8..f*8+7
#pragma unroll
    for (int o = 8; o <= 32; o <<= 1) {
#pragma unroll
        for (int j = 0; j < 8; j++) {
            accA[j] += __shfl_xor(accA[j], o);
            accB[j] += __shfl_xor(accB[j], o);
        }
    }
    float4 b0 = ((const float4*)bias)[2 * f];
    float4 b1 = ((const float4*)bias)[2 * f + 1];
    float rA[8], rB[8];
    rA[0] = fmaxf(accA[0] + b0.x, 0.f); rA[1] = fmaxf(accA[1] + b0.y, 0.f);
    rA[2] = fmaxf(accA[2] + b0.z, 0.f); rA[3] = fmaxf(accA[3] + b0.w, 0.f);
    rA[4] = fmaxf(accA[4] + b1.x, 0.f); rA[5] = fmaxf(accA[5] + b1.y, 0.f);
    rA[6] = fmaxf(accA[6] + b1.z, 0.f); rA[7] = fmaxf(accA[7] + b1.w, 0.f);
    rB[0] = fmaxf(accB[0] + b0.x, 0.f); rB[1] = fmaxf(accB[1] + b0.y, 0.f);
    rB[2] = fmaxf(accB[2] + b0.z, 0.f); rB[3] = fmaxf(accB[3] + b0.w, 0.f);
    rB[4] = fmaxf(accB[4] + b1.x, 0.f); rB[5] = fmaxf(accB[5] + b1.y, 0.f);
    rB[6] = fmaxf(accB[6] + b1.z, 0.f); rB[7] = fmaxf(accB[7] + b1.w, 0.f);
    if constexpr (!FUSE) {
        if (eg == 0) {
            uint4 pv;
            pv.x = (unsigned)f2bf(rA[0]) | ((unsigned)f2bf(rA[1]) << 16);
            pv.y = (unsigned)f2bf(rA[2]) | ((unsigned)f2bf(rA[3]) << 16);
            pv.z = (unsigned)f2bf(rA[4]) | ((unsigned)f2bf(rA[5]) << 16);
            pv.w = (unsigned)f2bf(rA[6]) | ((unsigned)f2bf(rA[7]) << 16);
            ((uint4*)out16)[nodeA * 8 + f] = pv;
            pv.x = (unsigned)f2bf(rB[0]) | ((unsigned)f2bf(rB[1]) << 16);
            pv.y = (unsigned)f2bf(rB[2]) | ((unsigned)f2bf(rB[3]) << 16);
            pv.z = (unsigned)f2bf(rB[4]) | ((unsigned)f2bf(rB[5]) << 16);
            pv.w = (unsigned)f2bf(rB[6]) | ((unsigned)f2bf(rB[7]) << 16);
            ((uint4*)out16)[nodeB * 8 + f] = pv;
        }
    } else {
        // h3[j] = sum_k row[k]*W3[k][j]; lane (f,eg): partial of output j=eg over
        // k = f*8..f*8+7, then 3-step reduce over f. Banks: 2-way only (9-pad).
        float pA = 0.f, pB = 0.f;
#pragma unroll
        for (int i = 0; i < 8; i++) {
            float w = W3p[(f * 8 + i) * 9 + eg];
            pA += rA[i] * w;
            pB += rB[i] * w;
        }
#pragma unroll
        for (int o = 1; o < 8; o <<= 1) {
            pA += __shfl_xor(pA, o);
            pB += __shfl_xor(pB, o);
        }
        float a3se = a3s[eg], a3de = a3d[eg];
        float vsA = pA * a3se, vdA = pA * a3de;
        float vsB = pB * a3se, vdB = pB * a3de;
#pragma unroll
        for (int o = 8; o <= 32; o <<= 1) {
            vsA += __shfl_xor(vsA, o); vdA += __shfl_xor(vdA, o);
            vsB += __shfl_xor(vsB, o); vdB += __shfl_xor(vdB, o);
        }
        if (lane == 0) { as3[nodeA] = vsA; ad3[nodeA] = vdA; as3[nodeB] = vsB; ad3[nodeB] = vdB; }
        if (f == 0) {
            out16[nodeA * 8 + eg] = f2bf(pA);
            out16[nodeB * 8 + eg] = f2bf(pB);
        }
    }
}

// ---------------- layer-3 aggregation (8 features, 16B rows), 2 nodes/wave ----------------

__global__ __launch_bounds__(256) void k_agg8(const unsigned short* __restrict__ h,
                                              const int* __restrict__ rowptr,
                                              const int* __restrict__ col, const float* __restrict__ as_,
                                              const float* __restrict__ ad_, const float* __restrict__ bias,
                                              float* __restrict__ out) {
    int wid = threadIdx.x >> 6;
    int lane = threadIdx.x & 63;
    int nodeA = blockIdx.x * 8 + wid * 2;
    int nodeB = nodeA + 1;
    int rpA = rowptr[nodeA];
    int rpB = rowptr[nodeB];
    int degA = rpB - rpA;
    int degB = rowptr[nodeB + 1] - rpB;
    float adnA = ad_[nodeA], adnB = ad_[nodeB];
    float zselfA = lrelu(as_[nodeA] + adnA);
    float zselfB = lrelu(as_[nodeB] + adnB);
    const uint2* h2 = (const uint2*)h;   // row = 2 x uint2 (4 bf16 each)
    int f = lane & 1, eg = lane >> 1;    // 32 edges in parallel, 8B per lane
    float accA[4] = {0.f, 0.f, 0.f, 0.f};
    float accB[4] = {0.f, 0.f, 0.f, 0.f};
    if (degA <= 32 && degB <= 32) {
        float zA = -1e30f, zB = -1e30f;
        uint2 rrA = make_uint2(0u, 0u), rrB = make_uint2(0u, 0u);
        if (eg < degA) {
            int se = col[rpA + eg];
            zA = lrelu(as_[se] + adnA);
            rrA = h2[se * 2 + f];
        }
        if (eg < degB) {
            int se = col[rpB + eg];
            zB = lrelu(as_[se] + adnB);
            rrB = h2[se * 2 + f];
        }
        float MA = zA, MB = zB;
#pragma unroll
        for (int o = 2; o <= 32; o <<= 1) {
            MA = fmaxf(MA, __shfl_xor(MA, o));
            MB = fmaxf(MB, __shfl_xor(MB, o));
        }
        MA = fmaxf(MA, zselfA); MB = fmaxf(MB, zselfB);
        float exA = __expf(zA - MA), exB = __expf(zB - MB);
        float exsA = __expf(zselfA - MA), exsB = __expf(zselfB - MB);
        float sA = exA, sB = exB;
#pragma unroll
        for (int o = 2; o <= 32; o <<= 1) {
            sA += __shfl_xor(sA, o);
            sB += __shfl_xor(sB, o);
        }
        float invA = 1.f / (sA + exsA), invB = 1.f / (sB + exsB);
        float wA = exA * invA, wB = exB * invB;
        float2 lA = bf2x2(rrA.x), hA = bf2x2(rrA.y);
        accA[0] = wA * lA.x; accA[1] = wA * lA.y; accA[2] = wA * hA.x; accA[3] = wA * hA.y;
        float2 lB = bf2x2(rrB.x), hB = bf2x2(rrB.y);
        accB[0] = wB * lB.x; accB[1] = wB * lB.y; accB[2] = wB * hB.x; accB[3] = wB * hB.y;
        if (eg == 0) {
            float w0A = exsA * invA;
            uint2 hvA = h2[nodeA * 2 + f];
            float2 l2 = bf2x2(hvA.x), h2v = bf2x2(hvA.y);
            accA[0] += w0A * l2.x; accA[1] += w0A * l2.y;
            accA[2] += w0A * h2v.x; accA[3] += w0A * h2v.y;
            float w0B = exsB * invB;
            uint2 hvB = h2[nodeB * 2 + f];
            float2 l2b = bf2x2(hvB.x), h2b = bf2x2(hvB.y);
            accB[0] += w0B * l2b.x; accB[1] += w0B * l2b.y;
            accB[2] += w0B * h2b.x; accB[3] += w0B * h2b.y;
        }
    } else {  // rare: per-node full-wave paths
#pragma unroll
        for (int half = 0; half < 2; half++) {
            int node = half ? nodeB : nodeA;
            int rp0 = half ? rpB : rpA;
            int deg = half ? degB : degA;
            float adn = half ? adnB : adnA;
            float zself = half ? zselfB : zselfA;
            float (&acc)[4] = half ? accB : accA;
            if (deg <= 32) {
                float z = -1e30f;
                uint2 rr = make_uint2(0u, 0u);
                if (eg < deg) {
                    int se = col[rp0 + eg];
                    z = lrelu(as_[se] + adn);
                    rr = h2[se * 2 + f];
                }
                float M = z;
#pragma unroll
                for (int o = 2; o <= 32; o <<= 1) M = fmaxf(M, __shfl_xor(M, o));
                M = fmaxf(M, zself);
                float ex = __expf(z - M);
                float exs = __expf(zself - M);
                float sum = ex;
#pragma unroll
                for (int o = 2; o <= 32; o <<= 1) sum += __shfl_xor(sum, o);
                float inv = 1.f / (sum + exs);
                float w = ex * inv;
                float2 lo = bf2x2(rr.x), hi = bf2x2(rr.y);
                acc[0] = w * lo.x; acc[1] = w * lo.y; acc[2] = w * hi.x; acc[3] = w * hi.y;
                if (eg == 0) {
                    float w0 = exs * inv;
                    uint2 hv = h2[node * 2 + f];
                    float2 l2 = bf2x2(hv.x), h2v = bf2x2(hv.y);
                    acc[0] += w0 * l2.x; acc[1] += w0 * l2.y;
                    acc[2] += w0 * h2v.x; acc[3] += w0 * h2v.y;
                }
            } else {
                float m = -1e30f, l = 0.f;
                for (int i = lane; i < deg; i += 64) {
                    float z = lrelu(as_[col[rp0 + i]] + adn);
                    float mn = fmaxf(m, z);
                    l = l * __expf(m - mn) + __expf(z - mn);
                    m = mn;
                }
                if (lane == 0) {
                    float mn = fmaxf(m, zself);
                    l = l * __expf(m - mn) + __expf(zself - mn);
                    m = mn;
                }
#pragma unroll
                for (int o = 32; o; o >>= 1) {
                    float mo = __shfl_xor(m, o), lo = __shfl_xor(l, o);
                    float mn = fmaxf(m, mo);
                    l = l * __expf(m - mn) + lo * __expf(mo - mn);
                    m = mn;
                }
                float Em = m;
                float inv = 1.f / l;
                for (int base = 0; base < deg; base += 32) {
                    int i = base + eg;
                    if (i < deg) {
                        int sv = col[rp0 + i];
                        float al = __expf(lrelu(as_[sv] + adn) - Em) * inv;
                        uint2 hv = h2[sv * 2 + f];
                        float2 lo = bf2x2(hv.x), hi = bf2x2(hv.y);
                        acc[0] += al * lo.x; acc[1] += al * lo.y;
                        acc[2] += al * hi.x; acc[3] += al * hi.y;
                    }
                }
                if (eg == 0) {
                    float al = __expf(zself - Em) * inv;
                    uint2 hv = h2[node * 2 + f];
                    float2 lo = bf2x2(hv.x), hi = bf2x2(hv.y);
                    acc[0] += al * lo.x; acc[1] += al * lo.y;
                    acc[2] += al * hi.x; acc[3] += al * hi.y;
                }
            }
        }
    }
#pragma unroll
    for (int o = 2; o <= 32; o <<= 1) {
#pragma unroll
        for (int j = 0; j < 4; j++) {
            accA[j] += __shfl_xor(accA[j], o);
            accB[j] += __shfl_xor(accB[j], o);
        }
    }
    if (eg == 0) {
        float4 bv = ((const float4*)bias)[f];
        float4 o4;
        o4.x = fmaxf(accA[0] + bv.x, 0.f);
        o4.y = fmaxf(accA[1] + bv.y, 0.f);
        o4.z = fmaxf(accA[2] + bv.z, 0.f);
        o4.w = fmaxf(accA[3] + bv.w, 0.f);
        ((float4*)out)[nodeA * 2 + f] = o4;
        o4.x = fmaxf(accB[0] + bv.x, 0.f);
        o4.y = fmaxf(accB[1] + bv.y, 0.f);
        o4.z = fmaxf(accB[2] + bv.z, 0.f);
        o4.w = fmaxf(accB[3] + bv.w, 0.f);
        ((float4*)out)[nodeB * 2 + f] = o4;
    }
}

// ---------------- k9: mean-pool + sigmoid (196 blocks, done-ticket; R9/R10-verified) ----------------

__global__ __launch_bounds__(256) void k9_poolfinal(const float* __restrict__ h3, const int* __restrict__ batch,
                                                    float* __restrict__ pool, float* __restrict__ cntf,
                                                    float* __restrict__ out) {
    __shared__ float pl[GG * CC + GG];
    __shared__ int lastFlag;
    int t = threadIdx.x;
    for (int idx = t; idx < GG * CC + GG; idx += 256) pl[idx] = 0.f;
    __syncthreads();
    int node = blockIdx.x * 256 + t;
    if (node < NN) {
        int g = batch[node];
#pragma unroll
        for (int c = 0; c < CC; c++) atomicAdd(&pl[g * CC + c], h3[node * CC + c]);
        atomicAdd(&pl[GG * CC + g], 1.0f);
    }
    __syncthreads();
    for (int idx = t; idx < GG * CC + GG; idx += 256) {
        float v = pl[idx];
        if (idx < GG * CC)
            atomicAdd(&pool[idx], v);
        else
            atomicAdd(&cntf[idx - GG * CC], v);
    }
    __syncthreads();
    if (t == 0) {
        __threadfence();
        unsigned r = __hip_atomic_fetch_add(&g_done, 1u, __ATOMIC_ACQ_REL, __HIP_MEMORY_SCOPE_AGENT);
        lastFlag = (r == (unsigned)(NBKT - 1));
    }
    __syncthreads();
    if (lastFlag) {
        __threadfence();
        for (int i = t; i < GG * CC; i += 256) {
            int g = i >> 3;
            float c = __hip_atomic_load(&cntf[g], __ATOMIC_RELAXED, __HIP_MEMORY_SCOPE_AGENT);
            float p = __hip_atomic_load(&pool[i], __ATOMIC_RELAXED, __HIP_MEMORY_SCOPE_AGENT);
            float v = p / fmaxf(c, 1.0f);
            out[i] = 1.0f / (1.0f + __expf(-v));
        }
        if (t == 0)
            __hip_atomic_store(&g_done, 0u, __ATOMIC_RELAXED, __HIP_MEMORY_SCOPE_AGENT);
    }
}

// ---------------- launch ----------------

extern "C" void kernel_launch(void* const* d_in, const int* in_sizes, int n_in,
                              void* d_out, int out_size, void* d_ws, size_t ws_size,
                              hipStream_t stream) {
    const float* x   = (const float*)d_in[0];
    const int*   ei  = (const int*)d_in[1];
    const int*   bat = (const int*)d_in[3];
    const float* W1  = (const float*)d_in[4];
    const float* a1s = (const float*)d_in[5];
    const float* a1d = (const float*)d_in[6];
    const float* b1  = (const float*)d_in[7];
    const float* W2  = (const float*)d_in[8];
    const float* a2s = (const float*)d_in[9];
    const float* a2d = (const float*)d_in[10];
    const float* b2  = (const float*)d_in[11];
    const float* W3  = (const float*)d_in[12];
    const float* a3s = (const float*)d_in[13];
    const float* a3d = (const float*)d_in[14];
    const float* b3  = (const float*)d_in[15];
    float* out = (float*)d_out;

    // workspace carve-up
    float* fb = (float*)d_ws;
    unsigned short* hA16 = (unsigned short*)fb;              // N*64 bf16 (N*32 floats)
    unsigned short* hB16 = (unsigned short*)(fb + NN * 32);  // N*64 bf16
    unsigned short* h316 = (unsigned short*)(fb + NN * 64);  // N*8 bf16 (N*4 floats)
    float* h3b  = fb + NN * 64 + NN * 4;                     // N*8 f32
    float* as_  = h3b + NN * 8;                              // N
    float* ad_  = as_ + NN;                                  // N
    float* as3  = ad_ + NN;                                  // N
    float* ad3  = as3 + NN;                                  // N
    int* rowptr = (int*)(ad3 + NN);                          // N+1
    int* col    = rowptr + NN + 1;                           // E
    int* G      = col + EE;                                  // NCHK*NBKT
    int* offs   = G + NCHK * NBKT;                           // NCHK*NBKT
    int* bT     = offs + NCHK * NBKT;                        // 256 (padded)
    unsigned* pairs = (unsigned*)(bT + 256);                 // E
    float* pool = (float*)(pairs + EE);                      // G*C
    float* cntf = pool + GG * CC;                            // G

    const int NB64 = (NN + 63) / 64;     // 782 (= NCHK)

    const int* srcE = ei;
    const int* dstE = ei + EE;

    k0_mm11_hist<<<NB64, 256, 0, stream>>>(x, W1, a1s, a1d, hA16, as_, ad_, dstE, G);
    k1_scan<<<NBKT, 256, 0, stream>>>(G, offs, bT, pool, cntf, rowptr);
    k2_part<<<NCHK, 256, 0, stream>>>(srcE, dstE, offs, bT, pairs);
    k3_sort<<<NBKT, 256, 0, stream>>>(pairs, bT, col, rowptr);

    k_agg64<false><<<NB8G, 256, 0, stream>>>(hA16, rowptr, col, as_, ad_, b1, hB16,
                                             nullptr, nullptr, nullptr, nullptr, nullptr);
    k_mm64t<<<NB64, 256, 0, stream>>>(hB16, W2, a2s, a2d, hA16, as_, ad_);
    k_agg64<true><<<NB8G, 256, 0, stream>>>(hA16, rowptr, col, as_, ad_, b2, h316,
                                            W3, a3s, a3d, as3, ad3);
    k_agg8<<<NB8G, 256, 0, stream>>>(h316, rowptr, col, as3, ad3, b3, h3b);
    k9_poolfinal<<<NBKT, 256, 0, stream>>>(h3b, bat, pool, cntf, out);
}

// Round 7
// 263.453 us; speedup vs baseline: 1.0686x; 1.0686x over previous
//
#include <hip/hip_runtime.h>

#define NN 50000
#define EE 800000
#define GG 64
#define CC 8

#define NBKT 196      // ceil(50000/256) node buckets of 256
#define NCHK 782      // edge chunks = grid of k0 (1024 edges each)
#define CHUNK 1024
#define CAP 8192      // max edges per bucket (mean 4082)
#define NB4G 12500    // agg grids: NN/4

// done-ticket for fused pool+sigmoid (196-block grid ONLY — R11 lesson: never on big grids)
__device__ unsigned g_done = 0;

__device__ __forceinline__ float lrelu(float z) { return fmaxf(z, 0.2f * z); }
__device__ __forceinline__ unsigned short f2bf(float v) {
    unsigned u = __float_as_uint(v);
    return (unsigned short)((u + 0x7FFFu + ((u >> 16) & 1u)) >> 16);  // RNE
}
__device__ __forceinline__ float bf2f(unsigned short b) {
    return __uint_as_float(((unsigned)b) << 16);
}
// unpack 2 bf16 from one dword: 1 VALU op per value
__device__ __forceinline__ float2 bf2x2(unsigned d) {
    float2 r;
    r.x = __uint_as_float(d << 16);
    r.y = __uint_as_float(d & 0xFFFF0000u);
    return r;
}

// ---------------- k0: layer-1 matmul (CSR-independent) fused with edge histogram ----------------
// R14 lesson: hist stays in LDS (global atomics = ~40 µs/800k-pass).
// R16 lesson: 196 buckets — k1's column reads of G scale with bucket count.

__global__ __launch_bounds__(256) void k0_mm11_hist(const float* __restrict__ x, const float* __restrict__ W,
                                                    const float* __restrict__ avs, const float* __restrict__ avd,
                                                    unsigned short* __restrict__ h, float* __restrict__ as_,
                                                    float* __restrict__ ad_, const int* __restrict__ dst,
                                                    int* __restrict__ G) {
    __shared__ float xT[11 * 68];
    __shared__ float Wl[11 * 64];
    __shared__ float avl[64], adl[64];
    __shared__ int hist[NBKT];
    int t = threadIdx.x;
    int nbase = blockIdx.x * 64;
    for (int idx = t; idx < 11 * 64; idx += 256) Wl[idx] = W[idx];
    if (t < 64) { avl[t] = avs[t]; adl[t] = avd[t]; }
    for (int idx = t; idx < 64 * 11; idx += 256) {
        int n = idx / 11, k = idx - n * 11;
        int gn = nbase + n;
        if (gn >= NN) gn = NN - 1;
        xT[k * 68 + n] = x[gn * 11 + k];
    }
    for (int i = t; i < NBKT; i += 256) hist[i] = 0;
    __syncthreads();
    int f0 = (t & 15) * 4;
    int n0 = (t >> 4) * 4;
    float a00=0,a01=0,a02=0,a03=0, a10=0,a11=0,a12=0,a13=0;
    float a20=0,a21=0,a22=0,a23=0, a30=0,a31=0,a32=0,a33=0;
#pragma unroll
    for (int k = 0; k < 11; k++) {
        float4 xv = *(const float4*)&xT[k * 68 + n0];
        float4 wv = *(const float4*)&Wl[k * 64 + f0];
        a00 += xv.x * wv.x; a01 += xv.x * wv.y; a02 += xv.x * wv.z; a03 += xv.x * wv.w;
        a10 += xv.y * wv.x; a11 += xv.y * wv.y; a12 += xv.y * wv.z; a13 += xv.y * wv.w;
        a20 += xv.z * wv.x; a21 += xv.z * wv.y; a22 += xv.z * wv.z; a23 += xv.z * wv.w;
        a30 += xv.w * wv.x; a31 += xv.w * wv.y; a32 += xv.w * wv.z; a33 += xv.w * wv.w;
    }
    float4 av = *(const float4*)&avl[f0];
    float4 dv = *(const float4*)&adl[f0];
    float vs[4], vd[4];
    vs[0] = a00*av.x + a01*av.y + a02*av.z + a03*av.w;
    vs[1] = a10*av.x + a11*av.y + a12*av.z + a13*av.w;
    vs[2] = a20*av.x + a21*av.y + a22*av.z + a23*av.w;
    vs[3] = a30*av.x + a31*av.y + a32*av.z + a33*av.w;
    vd[0] = a00*dv.x + a01*dv.y + a02*dv.z + a03*dv.w;
    vd[1] = a10*dv.x + a11*dv.y + a12*dv.z + a13*dv.w;
    vd[2] = a20*dv.x + a21*dv.y + a22*dv.z + a23*dv.w;
    vd[3] = a30*dv.x + a31*dv.y + a32*dv.z + a33*dv.w;
#pragma unroll
    for (int o = 1; o < 16; o <<= 1) {
#pragma unroll
        for (int ni = 0; ni < 4; ni++) {
            vs[ni] += __shfl_xor(vs[ni], o);
            vd[ni] += __shfl_xor(vd[ni], o);
        }
    }
    ushort4* h4 = (ushort4*)h;
    int nn0 = nbase + n0;
    float rows[4][4] = {{a00,a01,a02,a03},{a10,a11,a12,a13},{a20,a21,a22,a23},{a30,a31,a32,a33}};
#pragma unroll
    for (int ni = 0; ni < 4; ni++) {
        if (nn0 + ni < NN) {
            ushort4 pv;
            pv.x = f2bf(rows[ni][0]); pv.y = f2bf(rows[ni][1]);
            pv.z = f2bf(rows[ni][2]); pv.w = f2bf(rows[ni][3]);
            h4[(nn0 + ni) * 16 + (t & 15)] = pv;
            if ((t & 15) == 0) { as_[nn0 + ni] = vs[ni]; ad_[nn0 + ni] = vd[ni]; }
        }
    }
    int e0 = blockIdx.x * CHUNK;
    int e1 = min(e0 + CHUNK, EE);
    for (int e = e0 + t; e < e1; e += 256) atomicAdd(&hist[dst[e] >> 8], 1);
    __syncthreads();
    for (int i = t; i < NBKT; i += 256) G[blockIdx.x * NBKT + i] = hist[i];
}

// ---------------- k1: per-bucket scan across chunks; block 0 zeroes pool/cntf ----------------

__global__ __launch_bounds__(256) void k1_scan(const int* __restrict__ G, int* __restrict__ offs,
                                               int* __restrict__ bT, float* __restrict__ pool,
                                               float* __restrict__ cntf, int* __restrict__ rowptr) {
    __shared__ int s[256];
    int t = threadIdx.x, j = blockIdx.x;
    int c0 = t * 4;
    int v0 = (c0 + 0 < NCHK) ? G[(c0 + 0) * NBKT + j] : 0;
    int v1 = (c0 + 1 < NCHK) ? G[(c0 + 1) * NBKT + j] : 0;
    int v2 = (c0 + 2 < NCHK) ? G[(c0 + 2) * NBKT + j] : 0;
    int v3 = (c0 + 3 < NCHK) ? G[(c0 + 3) * NBKT + j] : 0;
    int tsum = v0 + v1 + v2 + v3;
    s[t] = tsum;
    __syncthreads();
#pragma unroll
    for (int off = 1; off < 256; off <<= 1) {
        int u = (t >= off) ? s[t - off] : 0;
        __syncthreads();
        s[t] += u;
        __syncthreads();
    }
    int excl = s[t] - tsum;
    if (c0 + 0 < NCHK) offs[(c0 + 0) * NBKT + j] = excl;
    if (c0 + 1 < NCHK) offs[(c0 + 1) * NBKT + j] = excl + v0;
    if (c0 + 2 < NCHK) offs[(c0 + 2) * NBKT + j] = excl + v0 + v1;
    if (c0 + 3 < NCHK) offs[(c0 + 3) * NBKT + j] = excl + v0 + v1 + v2;
    if (t == 255) bT[j] = s[255];
    if (j == 0) {
        for (int i = t; i < GG * CC; i += 256) pool[i] = 0.f;
        if (t < GG) cntf[t] = 0.f;
        if (t == 0) rowptr[NN] = EE;
    }
}

// ---------------- k2: partition edges into bucket-ordered packed pairs ----------------

__global__ __launch_bounds__(256) void k2_part(const int* __restrict__ src, const int* __restrict__ dst,
                                               const int* __restrict__ offs, const int* __restrict__ bT,
                                               unsigned* __restrict__ pairs) {
    __shared__ int s[256];
    __shared__ int bst[NBKT];
    __shared__ int cur[NBKT];
    int t = threadIdx.x, c = blockIdx.x;
    int v = (t < NBKT) ? bT[t] : 0;
    s[t] = v;
    __syncthreads();
#pragma unroll
    for (int off = 1; off < 256; off <<= 1) {
        int u = (t >= off) ? s[t - off] : 0;
        __syncthreads();
        s[t] += u;
        __syncthreads();
    }
    if (t < NBKT) bst[t] = s[t] - v;
    __syncthreads();
    for (int i = t; i < NBKT; i += 256) cur[i] = bst[i] + offs[c * NBKT + i];
    __syncthreads();
    int e0 = c * CHUNK, e1 = min(e0 + CHUNK, EE);
    for (int e = e0 + t; e < e1; e += 256) {
        int d = dst[e];
        int pos = atomicAdd(&cur[d >> 8], 1);
        pairs[pos] = (unsigned)src[e] | ((unsigned)(d & 255) << 16);  // src<2^16, dlocal<2^8
    }
}

// ---------------- k3: per-bucket counting sort -> col + rowptr ----------------
// R19: 1024-thread blocks. Grid is only 196 blocks (<=1/CU) and LDS is 34KB, so 256-thread
// blocks left ~77% of each CU idle; 16 waves/block quadruple staging parallelism. Scan
// ladders stay 256-wide (guarded) — they're short.

__global__ __launch_bounds__(1024) void k3_sort(const unsigned* __restrict__ pairs, const int* __restrict__ bT,
                                                int* __restrict__ col, int* __restrict__ rowptr) {
    __shared__ unsigned pL[CAP];
    __shared__ int hist[256];
    __shared__ int sc[256];
    int t = threadIdx.x, j = blockIdx.x;
    int v = (t < NBKT) ? bT[t] : 0;
    if (t < 256) hist[t] = v;
    __syncthreads();
#pragma unroll
    for (int off = 1; off < 256; off <<= 1) {
        int u = (t >= off && t < 256) ? hist[t - off] : 0;
        __syncthreads();
        if (t < 256) hist[t] += u;
        __syncthreads();
    }
    if (t == j) { sc[0] = hist[t] - v; sc[1] = v; }
    __syncthreads();
    int start = sc[0];
    int cnt = sc[1];
    if (cnt > CAP) cnt = CAP;
    int nb = j * 256;
    int nodeCnt = min(256, NN - nb);
    __syncthreads();
    if (t < 256) hist[t] = 0;
    __syncthreads();
    for (int i = t; i < cnt; i += 1024) {
        unsigned p = pairs[start + i];
        pL[i] = p;
        atomicAdd(&hist[p >> 16], 1);
    }
    __syncthreads();
    int c2 = (t < 256) ? hist[t] : 0;
    if (t < 256) sc[t] = c2;
    __syncthreads();
#pragma unroll
    for (int off = 1; off < 256; off <<= 1) {
        int u = (t >= off && t < 256) ? sc[t - off] : 0;
        __syncthreads();
        if (t < 256) sc[t] += u;
        __syncthreads();
    }
    int excl = (t < 256) ? (sc[t] - c2) : 0;
    if (t < nodeCnt) rowptr[nb + t] = start + excl;
    if (t < 256) hist[t] = excl;
    __syncthreads();
    for (int i = t; i < cnt; i += 1024) {
        unsigned p = pL[i];
        int pos = atomicAdd(&hist[p >> 16], 1);
        col[start + pos] = (int)(p & 0xFFFFu);
    }
}

// ---------------- tiled h = x @ W (64->64); bf16 in, bf16 out ----------------

__global__ __launch_bounds__(256) void k_mm64t(const unsigned short* __restrict__ xin,
                                               const float* __restrict__ W,
                                               const float* __restrict__ avs, const float* __restrict__ avd,
                                               unsigned short* __restrict__ h, float* __restrict__ as_,
                                               float* __restrict__ ad_) {
    __shared__ float xT[64 * 68];
    __shared__ float Wl[64 * 64];
    __shared__ float avl[64], adl[64];
    int t = threadIdx.x;
    int nbase = blockIdx.x * 64;
    for (int idx = t; idx < 64 * 64; idx += 256) Wl[idx] = W[idx];
    if (t < 64) { avl[t] = avs[t]; adl[t] = avd[t]; }
    for (int idx = t; idx < 64 * 64; idx += 256) {
        int n = idx / 64, k = idx - n * 64;
        int gn = nbase + n;
        if (gn >= NN) gn = NN - 1;
        xT[k * 68 + n] = bf2f(xin[gn * 64 + k]);
    }
    __syncthreads();
    int f0 = (t & 15) * 4;
    int n0 = (t >> 4) * 4;
    float a00=0,a01=0,a02=0,a03=0, a10=0,a11=0,a12=0,a13=0;
    float a20=0,a21=0,a22=0,a23=0, a30=0,a31=0,a32=0,a33=0;
#pragma unroll 4
    for (int k = 0; k < 64; k++) {
        float4 xv = *(const float4*)&xT[k * 68 + n0];
        float4 wv = *(const float4*)&Wl[k * 64 + f0];
        a00 += xv.x * wv.x; a01 += xv.x * wv.y; a02 += xv.x * wv.z; a03 += xv.x * wv.w;
        a10 += xv.y * wv.x; a11 += xv.y * wv.y; a12 += xv.y * wv.z; a13 += xv.y * wv.w;
        a20 += xv.z * wv.x; a21 += xv.z * wv.y; a22 += xv.z * wv.z; a23 += xv.z * wv.w;
        a30 += xv.w * wv.x; a31 += xv.w * wv.y; a32 += xv.w * wv.z; a33 += xv.w * wv.w;
    }
    float4 av = *(const float4*)&avl[f0];
    float4 dv = *(const float4*)&adl[f0];
    float vs[4], vd[4];
    vs[0] = a00*av.x + a01*av.y + a02*av.z + a03*av.w;
    vs[1] = a10*av.x + a11*av.y + a12*av.z + a13*av.w;
    vs[2] = a20*av.x + a21*av.y + a22*av.z + a23*av.w;
    vs[3] = a30*av.x + a31*av.y + a32*av.z + a33*av.w;
    vd[0] = a00*dv.x + a01*dv.y + a02*dv.z + a03*dv.w;
    vd[1] = a10*dv.x + a11*dv.y + a12*dv.z + a13*dv.w;
    vd[2] = a20*dv.x + a21*dv.y + a22*dv.z + a23*dv.w;
    vd[3] = a30*dv.x + a31*dv.y + a32*dv.z + a33*dv.w;
#pragma unroll
    for (int o = 1; o < 16; o <<= 1) {
#pragma unroll
        for (int ni = 0; ni < 4; ni++) {
            vs[ni] += __shfl_xor(vs[ni], o);
            vd[ni] += __shfl_xor(vd[ni], o);
        }
    }
    ushort4* h4 = (ushort4*)h;
    int nn0 = nbase + n0;
    float rows[4][4] = {{a00,a01,a02,a03},{a10,a11,a12,a13},{a20,a21,a22,a23},{a30,a31,a32,a33}};
#pragma unroll
    for (int ni = 0; ni < 4; ni++) {
        if (nn0 + ni < NN) {
            ushort4 pv;
            pv.x = f2bf(rows[ni][0]); pv.y = f2bf(rows[ni][1]);
            pv.z = f2bf(rows[ni][2]); pv.w = f2bf(rows[ni][3]);
            h4[(nn0 + ni) * 16 + (t & 15)] = pv;
            if ((t & 15) == 0) { as_[nn0 + ni] = vs[ni]; ad_[nn0 + ni] = vd[ni]; }
        }
    }
}

// ---------------- agg64 fast-path body, templated on kmax = ceil(deg/8) ----------------
// R17: deg is Poisson(16) -> avg kmax 2.44 of 4; KMAX dispatch is wave-uniform.
// Only the last k-block needs load predication. FMA side unpredicated (w=0 beyond deg).

template <int KMAX>
__device__ __forceinline__ void agg64_fast(int deg, int rp0, const int* __restrict__ col,
                                           const float* __restrict__ as_, float adn, float zself,
                                           const uint4* __restrict__ hb4, int node, int f, int eg,
                                           float (&acc)[8]) {
    uint4 rowreg[KMAX];
    float zk[KMAX];
#pragma unroll
    for (int k = 0; k < KMAX; k++) {
        int e = k * 8 + eg;
        zk[k] = -1e30f;
        rowreg[k] = make_uint4(0u, 0u, 0u, 0u);
        if (k < KMAX - 1 || e < deg) {
            int se = col[rp0 + e];
            zk[k] = lrelu(as_[se] + adn);
            rowreg[k] = hb4[se * 8 + f];
        }
    }
    float M = zk[0];
#pragma unroll
    for (int k = 1; k < KMAX; k++) M = fmaxf(M, zk[k]);
#pragma unroll
    for (int o = 8; o <= 32; o <<= 1) M = fmaxf(M, __shfl_xor(M, o));
    M = fmaxf(M, zself);
    float s0 = 0.f;
#pragma unroll
    for (int k = 0; k < KMAX; k++) { zk[k] = __expf(zk[k] - M); s0 += zk[k]; }  // exp reused as weight
    float exs = __expf(zself - M);
    float sum = s0;
#pragma unroll
    for (int o = 8; o <= 32; o <<= 1) sum += __shfl_xor(sum, o);
    float inv = 1.f / (sum + exs);
#pragma unroll
    for (int k = 0; k < KMAX; k++) {
        float w = zk[k] * inv;   // 0 for slots beyond deg
        float2 p0 = bf2x2(rowreg[k].x), p1 = bf2x2(rowreg[k].y);
        float2 p2 = bf2x2(rowreg[k].z), p3 = bf2x2(rowreg[k].w);
        acc[0] += w * p0.x; acc[1] += w * p0.y;
        acc[2] += w * p1.x; acc[3] += w * p1.y;
        acc[4] += w * p2.x; acc[5] += w * p2.y;
        acc[6] += w * p3.x; acc[7] += w * p3.y;
    }
    if (eg == 0) {
        float w0 = exs * inv;
        uint4 hv = hb4[node * 8 + f];
        float2 p0 = bf2x2(hv.x), p1 = bf2x2(hv.y), p2 = bf2x2(hv.z), p3 = bf2x2(hv.w);
        acc[0] += w0 * p0.x; acc[1] += w0 * p0.y;
        acc[2] += w0 * p1.x; acc[3] += w0 * p1.y;
        acc[4] += w0 * p2.x; acc[5] += w0 * p2.y;
        acc[6] += w0 * p3.x; acc[7] += w0 * p3.y;
    }
}

// ---------------- GAT aggregation, 64 features ----------------

template <bool FUSE>
__global__ __launch_bounds__(256) void k_agg64(const unsigned short* __restrict__ h,
                                               const int* __restrict__ rowptr,
                                               const int* __restrict__ col, const float* __restrict__ as_,
                                               const float* __restrict__ ad_, const float* __restrict__ bias,
                                               unsigned short* __restrict__ out16,
                                               const float* __restrict__ W3, const float* __restrict__ a3s,
                                               const float* __restrict__ a3d,
                                               float* __restrict__ as3, float* __restrict__ ad3) {
    __shared__ float W3p[64 * 9];  // FUSE only; pad 8->9: 2-way conflicts only (free, m136)
    if constexpr (FUSE) {
        for (int idx = threadIdx.x; idx < 512; idx += 256)
            W3p[(idx >> 3) * 9 + (idx & 7)] = W3[idx];
        __syncthreads();  // uniform: before any divergence
    }
    int wid = threadIdx.x >> 6;
    int node = blockIdx.x * 4 + wid;   // NN = 12500*4: every wave valid
    int lane = threadIdx.x & 63;
    int rp0 = rowptr[node];
    int deg = rowptr[node + 1] - rp0;
    float adn = ad_[node];
    float zself = lrelu(as_[node] + adn);
    const uint4* hb4 = (const uint4*)h;   // row = 8 x uint4 (8 bf16 per uint4)
    int f = lane & 7, eg = lane >> 3;     // 8 edges in parallel, 16B per lane
    float acc[8] = {0.f, 0.f, 0.f, 0.f, 0.f, 0.f, 0.f, 0.f};
    if (deg <= 32) {
        int kmax = (deg + 7) >> 3;  // wave-uniform
        switch (kmax) {
            case 1: agg64_fast<1>(deg, rp0, col, as_, adn, zself, hb4, node, f, eg, acc); break;
            case 2: agg64_fast<2>(deg, rp0, col, as_, adn, zself, hb4, node, f, eg, acc); break;
            case 3: agg64_fast<3>(deg, rp0, col, as_, adn, zself, hb4, node, f, eg, acc); break;
            case 4: agg64_fast<4>(deg, rp0, col, as_, adn, zself, hb4, node, f, eg, acc); break;
            default: {  // deg == 0: softmax over self only -> weight 1
                if (eg == 0) {
                    uint4 hv = hb4[node * 8 + f];
                    float2 p0 = bf2x2(hv.x), p1 = bf2x2(hv.y), p2 = bf2x2(hv.z), p3 = bf2x2(hv.w);
                    acc[0] = p0.x; acc[1] = p0.y; acc[2] = p1.x; acc[3] = p1.y;
                    acc[4] = p2.x; acc[5] = p2.y; acc[6] = p3.x; acc[7] = p3.y;
                }
            } break;
        }
    } else {  // rare fallback (deg>32): online softmax + direct gathers
        float m = -1e30f, l = 0.f;
        for (int i = lane; i < deg; i += 64) {
            float z = lrelu(as_[col[rp0 + i]] + adn);
            float mn = fmaxf(m, z);
            l = l * __expf(m - mn) + __expf(z - mn);
            m = mn;
        }
        if (lane == 0) {
            float mn = fmaxf(m, zself);
            l = l * __expf(m - mn) + __expf(zself - mn);
            m = mn;
        }
#pragma unroll
        for (int o = 32; o; o >>= 1) {
            float mo = __shfl_xor(m, o), lo = __shfl_xor(l, o);
            float mn = fmaxf(m, mo);
            l = l * __expf(m - mn) + lo * __expf(mo - mn);
            m = mn;
        }
        float Em = m;
        float inv = 1.f / l;
        for (int base = 0; base < deg; base += 8) {
            int i = base + eg;
            if (i < deg) {
                int sv = col[rp0 + i];
                float al = __expf(lrelu(as_[sv] + adn) - Em) * inv;
                uint4 hv = hb4[sv * 8 + f];
                float2 p0 = bf2x2(hv.x), p1 = bf2x2(hv.y), p2 = bf2x2(hv.z), p3 = bf2x2(hv.w);
                acc[0] += al * p0.x; acc[1] += al * p0.y;
                acc[2] += al * p1.x; acc[3] += al * p1.y;
                acc[4] += al * p2.x; acc[5] += al * p2.y;
                acc[6] += al * p3.x; acc[7] += al * p3.y;
            }
        }
        if (eg == 0) {
            float al = __expf(zself - Em) * inv;
            uint4 hv = hb4[node * 8 + f];
            float2 p0 = bf2x2(hv.x), p1 = bf2x2(hv.y), p2 = bf2x2(hv.z), p3 = bf2x2(hv.w);
            acc[0] += al * p0.x; acc[1] += al * p0.y;
            acc[2] += al * p1.x; acc[3] += al * p1.y;
            acc[4] += al * p2.x; acc[5] += al * p2.y;
            acc[6] += al * p3.x; acc[7] += al * p3.y;
        }
    }
    // reduce across the 8 eg groups; after this ALL lanes hold features f*8..f*8+7
#pragma unroll
    for (int o = 8; o <= 32; o <<= 1) {
#pragma unroll
        for (int j = 0; j < 8; j++) acc[j] += __shfl_xor(acc[j], o);
    }
    float4 b0 = ((const float4*)bias)[2 * f];
    float4 b1 = ((const float4*)bias)[2 * f + 1];
    float r[8];
    r[0] = fmaxf(acc[0] + b0.x, 0.f); r[1] = fmaxf(acc[1] + b0.y, 0.f);
    r[2] = fmaxf(acc[2] + b0.z, 0.f); r[3] = fmaxf(acc[3] + b0.w, 0.f);
    r[4] = fmaxf(acc[4] + b1.x, 0.f); r[5] = fmaxf(acc[5] + b1.y, 0.f);
    r[6] = fmaxf(acc[6] + b1.z, 0.f); r[7] = fmaxf(acc[7] + b1.w, 0.f);
    if constexpr (!FUSE) {
        if (eg == 0) {
            uint4 pv;
            pv.x = (unsigned)f2bf(r[0]) | ((unsigned)f2bf(r[1]) << 16);
            pv.y = (unsigned)f2bf(r[2]) | ((unsigned)f2bf(r[3]) << 16);
            pv.z = (unsigned)f2bf(r[4]) | ((unsigned)f2bf(r[5]) << 16);
            pv.w = (unsigned)f2bf(r[6]) | ((unsigned)f2bf(r[7]) << 16);
            ((uint4*)out16)[node * 8 + f] = pv;
        }
    } else {
        // h3[j] = sum_k row[k]*W3[k][j]; lane (f,eg): partial of output j=eg over
        // k = f*8..f*8+7, then 3-step reduce over f. Banks: 2-way only (9-pad).
        float p = 0.f;
#pragma unroll
        for (int i = 0; i < 8; i++) p += r[i] * W3p[(f * 8 + i) * 9 + eg];
#pragma unroll
        for (int o = 1; o < 8; o <<= 1) p += __shfl_xor(p, o);
        float vs = p * a3s[eg];
        float vd = p * a3d[eg];
#pragma unroll
        for (int o = 8; o <= 32; o <<= 1) { vs += __shfl_xor(vs, o); vd += __shfl_xor(vd, o); }
        if (lane == 0) { as3[node] = vs; ad3[node] = vd; }
        if (f == 0) out16[node * 8 + eg] = f2bf(p);
    }
}

// ---------------- layer-3 aggregation (8 features, 16B rows) ----------------

__global__ __launch_bounds__(256) void k_agg8(const unsigned short* __restrict__ h,
                                              const int* __restrict__ rowptr,
                                              const int* __restrict__ col, const float* __restrict__ as_,
                                              const float* __restrict__ ad_, const float* __restrict__ bias,
                                              float* __restrict__ out) {
    int wid = threadIdx.x >> 6;
    int node = blockIdx.x * 4 + wid;
    int lane = threadIdx.x & 63;
    int rp0 = rowptr[node];
    int deg = rowptr[node + 1] - rp0;
    float adn = ad_[node];
    float zself = lrelu(as_[node] + adn);
    const uint2* h2 = (const uint2*)h;   // row = 2 x uint2 (4 bf16 each)
    int f = lane & 1, eg = lane >> 1;    // 32 edges in parallel, 8B per lane
    float acc[4] = {0.f, 0.f, 0.f, 0.f};
    if (deg <= 32) {
        float z = -1e30f;
        uint2 rr = make_uint2(0u, 0u);
        if (eg < deg) {
            int se = col[rp0 + eg];        // broadcast load (2 lanes/address)
            z = lrelu(as_[se] + adn);
            rr = h2[se * 2 + f];
        }
        float M = z;
#pragma unroll
        for (int o = 2; o <= 32; o <<= 1) M = fmaxf(M, __shfl_xor(M, o));
        M = fmaxf(M, zself);
        float ex = __expf(z - M);          // 0 for inactive lanes
        float exs = __expf(zself - M);
        float sum = ex;
#pragma unroll
        for (int o = 2; o <= 32; o <<= 1) sum += __shfl_xor(sum, o);
        float inv = 1.f / (sum + exs);
        float w = ex * inv;
        float2 lo = bf2x2(rr.x), hi = bf2x2(rr.y);
        acc[0] = w * lo.x; acc[1] = w * lo.y; acc[2] = w * hi.x; acc[3] = w * hi.y;
        if (eg == 0) {
            float w0 = exs * inv;
            uint2 hv = h2[node * 2 + f];
            float2 l2 = bf2x2(hv.x), h2v = bf2x2(hv.y);
            acc[0] += w0 * l2.x; acc[1] += w0 * l2.y;
            acc[2] += w0 * h2v.x; acc[3] += w0 * h2v.y;
        }
    } else {  // rare fallback (deg>32)
        float m = -1e30f, l = 0.f;
        for (int i = lane; i < deg; i += 64) {
            float z = lrelu(as_[col[rp0 + i]] + adn);
            float mn = fmaxf(m, z);
            l = l * __expf(m - mn) + __expf(z - mn);
            m = mn;
        }
        if (lane == 0) {
            float mn = fmaxf(m, zself);
            l = l * __expf(m - mn) + __expf(zself - mn);
            m = mn;
        }
#pragma unroll
        for (int o = 32; o; o >>= 1) {
            float mo = __shfl_xor(m, o), lo = __shfl_xor(l, o);
            float mn = fmaxf(m, mo);
            l = l * __expf(m - mn) + lo * __expf(mo - mn);
            m = mn;
        }
        float Em = m;
        float inv = 1.f / l;
        for (int base = 0; base < deg; base += 32) {
            int i = base + eg;
            if (i < deg) {
                int sv = col[rp0 + i];
                float al = __expf(lrelu(as_[sv] + adn) - Em) * inv;
                uint2 hv = h2[sv * 2 + f];
                float2 lo = bf2x2(hv.x), hi = bf2x2(hv.y);
                acc[0] += al * lo.x; acc[1] += al * lo.y;
                acc[2] += al * hi.x; acc[3] += al * hi.y;
            }
        }
        if (eg == 0) {
            float al = __expf(zself - Em) * inv;
            uint2 hv = h2[node * 2 + f];
            float2 lo = bf2x2(hv.x), hi = bf2x2(hv.y);
            acc[0] += al * lo.x; acc[1] += al * lo.y;
            acc[2] += al * hi.x; acc[3] += al * hi.y;
        }
    }
#pragma unroll
    for (int o = 2; o <= 32; o <<= 1) {
#pragma unroll
        for (int j = 0; j < 4; j++) acc[j] += __shfl_xor(acc[j], o);
    }
    if (eg == 0) {
        float4 bv = ((const float4*)bias)[f];
        float4 o4;
        o4.x = fmaxf(acc[0] + bv.x, 0.f);
        o4.y = fmaxf(acc[1] + bv.y, 0.f);
        o4.z = fmaxf(acc[2] + bv.z, 0.f);
        o4.w = fmaxf(acc[3] + bv.w, 0.f);
        ((float4*)out)[node * 2 + f] = o4;
    }
}

// ---------------- k9: mean-pool + sigmoid (196 blocks, done-ticket; R9/R10-verified) ----------------

__global__ __launch_bounds__(256) void k9_poolfinal(const float* __restrict__ h3, const int* __restrict__ batch,
                                                    float* __restrict__ pool, float* __restrict__ cntf,
                                                    float* __restrict__ out) {
    __shared__ float pl[GG * CC + GG];
    __shared__ int lastFlag;
    int t = threadIdx.x;
    for (int idx = t; idx < GG * CC + GG; idx += 256) pl[idx] = 0.f;
    __syncthreads();
    int node = blockIdx.x * 256 + t;
    if (node < NN) {
        int g = batch[node];
#pragma unroll
        for (int c = 0; c < CC; c++) atomicAdd(&pl[g * CC + c], h3[node * CC + c]);
        atomicAdd(&pl[GG * CC + g], 1.0f);
    }
    __syncthreads();
    for (int idx = t; idx < GG * CC + GG; idx += 256) {
        float v = pl[idx];
        if (idx < GG * CC)
            atomicAdd(&pool[idx], v);
        else
            atomicAdd(&cntf[idx - GG * CC], v);
    }
    __syncthreads();
    if (t == 0) {
        __threadfence();
        unsigned r = __hip_atomic_fetch_add(&g_done, 1u, __ATOMIC_ACQ_REL, __HIP_MEMORY_SCOPE_AGENT);
        lastFlag = (r == (unsigned)(NBKT - 1));
    }
    __syncthreads();
    if (lastFlag) {
        __threadfence();
        for (int i = t; i < GG * CC; i += 256) {
            int g = i >> 3;
            float c = __hip_atomic_load(&cntf[g], __ATOMIC_RELAXED, __HIP_MEMORY_SCOPE_AGENT);
            float p = __hip_atomic_load(&pool[i], __ATOMIC_RELAXED, __HIP_MEMORY_SCOPE_AGENT);
            float v = p / fmaxf(c, 1.0f);
            out[i] = 1.0f / (1.0f + __expf(-v));
        }
        if (t == 0)
            __hip_atomic_store(&g_done, 0u, __ATOMIC_RELAXED, __HIP_MEMORY_SCOPE_AGENT);
    }
}

// ---------------- launch ----------------

extern "C" void kernel_launch(void* const* d_in, const int* in_sizes, int n_in,
                              void* d_out, int out_size, void* d_ws, size_t ws_size,
                              hipStream_t stream) {
    const float* x   = (const float*)d_in[0];
    const int*   ei  = (const int*)d_in[1];
    const int*   bat = (const int*)d_in[3];
    const float* W1  = (const float*)d_in[4];
    const float* a1s = (const float*)d_in[5];
    const float* a1d = (const float*)d_in[6];
    const float* b1  = (const float*)d_in[7];
    const float* W2  = (const float*)d_in[8];
    const float* a2s = (const float*)d_in[9];
    const float* a2d = (const float*)d_in[10];
    const float* b2  = (const float*)d_in[11];
    const float* W3  = (const float*)d_in[12];
    const float* a3s = (const float*)d_in[13];
    const float* a3d = (const float*)d_in[14];
    const float* b3  = (const float*)d_in[15];
    float* out = (float*)d_out;

    // workspace carve-up
    float* fb = (float*)d_ws;
    unsigned short* hA16 = (unsigned short*)fb;              // N*64 bf16 (N*32 floats)
    unsigned short* hB16 = (unsigned short*)(fb + NN * 32);  // N*64 bf16
    unsigned short* h316 = (unsigned short*)(fb + NN * 64);  // N*8 bf16 (N*4 floats)
    float* h3b  = fb + NN * 64 + NN * 4;                     // N*8 f32
    float* as_  = h3b + NN * 8;                              // N
    float* ad_  = as_ + NN;                                  // N
    float* as3  = ad_ + NN;                                  // N
    float* ad3  = as3 + NN;                                  // N
    int* rowptr = (int*)(ad3 + NN);                          // N+1
    int* col    = rowptr + NN + 1;                           // E
    int* G      = col + EE;                                  // NCHK*NBKT
    int* offs   = G + NCHK * NBKT;                           // NCHK*NBKT
    int* bT     = offs + NCHK * NBKT;                        // 256 (padded)
    unsigned* pairs = (unsigned*)(bT + 256);                 // E
    float* pool = (float*)(pairs + EE);                      // G*C
    float* cntf = pool + GG * CC;                            // G

    const int NB64 = (NN + 63) / 64;     // 782 (= NCHK)

    const int* srcE = ei;
    const int* dstE = ei + EE;

    k0_mm11_hist<<<NB64, 256, 0, stream>>>(x, W1, a1s, a1d, hA16, as_, ad_, dstE, G);
    k1_scan<<<NBKT, 256, 0, stream>>>(G, offs, bT, pool, cntf, rowptr);
    k2_part<<<NCHK, 256, 0, stream>>>(srcE, dstE, offs, bT, pairs);
    k3_sort<<<NBKT, 1024, 0, stream>>>(pairs, bT, col, rowptr);

    k_agg64<false><<<NB4G, 256, 0, stream>>>(hA16, rowptr, col, as_, ad_, b1, hB16,
                                             nullptr, nullptr, nullptr, nullptr, nullptr);
    k_mm64t<<<NB64, 256, 0, stream>>>(hB16, W2, a2s, a2d, hA16, as_, ad_);
    k_agg64<true><<<NB4G, 256, 0, stream>>>(hA16, rowptr, col, as_, ad_, b2, h316,
                                            W3, a3s, a3d, as3, ad3);
    k_agg8<<<NB4G, 256, 0, stream>>>(h316, rowptr, col, as3, ad3, b3, h3b);
    k9_poolfinal<<<NBKT, 256, 0, stream>>>(h3b, bat, pool, cntf, out);
}